// Round 9
// baseline (225.704 us; speedup 1.0000x reference)
//
#include <hip/hip_runtime.h>

typedef unsigned short u16;
typedef unsigned int u32;
typedef __bf16 bf16x8 __attribute__((ext_vector_type(8)));
typedef float f32x4 __attribute__((ext_vector_type(4)));

#define N_NODES 10000
#define N_EDGES 160000
#define D_IN 512
#define D_HID 1024

#define AS1 __attribute__((address_space(1)))
#define AS3 __attribute__((address_space(3)))

// padded LDS row pitches (in bf16 elems)
#define PA 520    // sA: 512 + 8
#define PH 1032   // sH: 1024 + 8

__device__ __forceinline__ u16 f2bf(float f) {
    union { float f; u32 u; } v; v.f = f;
    return (u16)((v.u + 0x7fffu + ((v.u >> 16) & 1u)) >> 16);
}
__device__ __forceinline__ float b2f(u32 h) {
    union { u32 u; float f; } v; v.u = h << 16; return v.f;
}

// ---- CSR build: histogram of dst ----
__global__ void hist_k(const int* __restrict__ dst, int* __restrict__ counts) {
    int e = blockIdx.x * 256 + threadIdx.x;
    if (e < N_EDGES) atomicAdd(&counts[dst[e]], 1);
}

// ---- single-block scan via wave shuffles: offs[10001], cursor[10000] ----
__global__ __launch_bounds__(1024) void scan_k(const int* __restrict__ counts,
                                               int* __restrict__ offs,
                                               int* __restrict__ cursor) {
    __shared__ int wpre[16];
    int t = threadIdx.x, l = t & 63, w = t >> 6;
    int base = t * 10;
    int c[10];
    int lsum = 0;
#pragma unroll
    for (int i = 0; i < 10; i++) {
        int idx = base + i;
        c[i] = (idx < N_NODES) ? counts[idx] : 0;
        lsum += c[i];
    }
    int sc = lsum;
#pragma unroll
    for (int d = 1; d < 64; d <<= 1) {
        int v = __shfl_up(sc, d);
        if (l >= d) sc += v;
    }
    __shared__ int wsum[16];
    if (l == 63) wsum[w] = sc;
    __syncthreads();
    if (w == 0 && l < 16) {
        int v = wsum[l];
        int p = v;
#pragma unroll
        for (int d = 1; d < 16; d <<= 1) {
            int u = __shfl_up(p, d);
            if (l >= d) p += u;
        }
        wpre[l] = p - v;
    }
    __syncthreads();
    int run = wpre[w] + sc - lsum;
#pragma unroll
    for (int i = 0; i < 10; i++) {
        int idx = base + i;
        if (idx < N_NODES) { offs[idx] = run; cursor[idx] = run; run += c[i]; }
    }
    if (t == 1023) offs[N_NODES] = wpre[15] + sc;
}

// ---- reorder edges into dst-sorted order ----
__global__ void reorder_k(const int* __restrict__ src, const int* __restrict__ dst,
                          int* __restrict__ cursor, int* __restrict__ ssrc) {
    int e = blockIdx.x * 256 + threadIdx.x;
    if (e >= N_EDGES) return;
    int d = dst[e];
    int pos = atomicAdd(&cursor[d], 1);
    ssrc[pos] = src[e];
}

// ---- fp32 -> bf16 convert (feat copy), 8 elems/thread ----
__global__ void cvt_bf16_k(const float* __restrict__ in, u16* __restrict__ out, int n) {
    int i = (blockIdx.x * 256 + threadIdx.x) * 8;
    if (i >= n) return;
    float4 a = *(const float4*)(in + i);
    float4 b = *(const float4*)(in + i + 4);
    uint4 o;
    o.x = (u32)f2bf(a.x) | ((u32)f2bf(a.y) << 16);
    o.y = (u32)f2bf(a.z) | ((u32)f2bf(a.w) << 16);
    o.z = (u32)f2bf(b.x) | ((u32)f2bf(b.y) << 16);
    o.w = (u32)f2bf(b.z) | ((u32)f2bf(b.w) << 16);
    *(uint4*)(out + i) = o;
}

// ---- fused W1/W2 transpose+convert: WT[n][k] = bf16(W[k][n]) ----
__global__ void transw_k(const float* __restrict__ W1, u16* __restrict__ w1t,
                         const float* __restrict__ W2, u16* __restrict__ w2t) {
    __shared__ float tile[32][33];
    int b = blockIdx.x;
    const float* W; u16* WT; int K, N, nt;
    if (b < 512) { W = W1; WT = w1t; K = D_IN;  N = D_HID; nt = 32; }
    else         { b -= 512; W = W2; WT = w2t; K = D_HID; N = D_IN;  nt = 16; }
    int n0 = (b % nt) * 32, k0 = (b / nt) * 32;
    int tx = threadIdx.x, ty = threadIdx.y;
#pragma unroll
    for (int i = 0; i < 32; i += 8)
        tile[ty + i][tx] = W[(size_t)(k0 + ty + i) * N + n0 + tx];
    __syncthreads();
#pragma unroll
    for (int i = 0; i < 32; i += 8)
        WT[(size_t)(n0 + ty + i) * K + k0 + tx] = f2bf(tile[tx][ty + i]);
}

// ---- gather-sum from bf16 feat + (1+eps)*fp32 self, write bf16 ----
__global__ __launch_bounds__(128) void gather_k(const float* __restrict__ feat,
                                                const u16* __restrict__ featb,
                                                const float* __restrict__ eps,
                                                const int* __restrict__ offs,
                                                const int* __restrict__ ssrc,
                                                u16* __restrict__ out) {
    int n = (blockIdx.x * 128 + threadIdx.x) >> 6;
    int l = threadIdx.x & 63;
    if (n >= N_NODES) return;
    int beg = offs[n], end = offs[n + 1];
    float s = 1.0f + eps[0];
    float4 s0 = *(const float4*)(feat + (size_t)n * D_IN + l * 8);
    float4 s1 = *(const float4*)(feat + (size_t)n * D_IN + l * 8 + 4);
    float acc[8] = { s * s0.x, s * s0.y, s * s0.z, s * s0.w,
                     s * s1.x, s * s1.y, s * s1.z, s * s1.w };
    int e = beg;
    for (; e + 4 <= end; e += 4) {
        int i0 = ssrc[e], i1 = ssrc[e + 1], i2 = ssrc[e + 2], i3 = ssrc[e + 3];
        uint4 v0 = *(const uint4*)(featb + (size_t)i0 * D_IN + l * 8);
        uint4 v1 = *(const uint4*)(featb + (size_t)i1 * D_IN + l * 8);
        uint4 v2 = *(const uint4*)(featb + (size_t)i2 * D_IN + l * 8);
        uint4 v3 = *(const uint4*)(featb + (size_t)i3 * D_IN + l * 8);
#define ACC4(v) \
        acc[0] += b2f(v.x & 0xffffu); acc[1] += b2f(v.x >> 16); \
        acc[2] += b2f(v.y & 0xffffu); acc[3] += b2f(v.y >> 16); \
        acc[4] += b2f(v.z & 0xffffu); acc[5] += b2f(v.z >> 16); \
        acc[6] += b2f(v.w & 0xffffu); acc[7] += b2f(v.w >> 16);
        ACC4(v0) ACC4(v1) ACC4(v2) ACC4(v3)
    }
    for (; e < end; e++) {
        int i0 = ssrc[e];
        uint4 v0 = *(const uint4*)(featb + (size_t)i0 * D_IN + l * 8);
        ACC4(v0)
    }
#undef ACC4
    uint4 o;
    o.x = (u32)f2bf(acc[0]) | ((u32)f2bf(acc[1]) << 16);
    o.y = (u32)f2bf(acc[2]) | ((u32)f2bf(acc[3]) << 16);
    o.z = (u32)f2bf(acc[4]) | ((u32)f2bf(acc[5]) << 16);
    o.w = (u32)f2bf(acc[6]) | ((u32)f2bf(acc[7]) << 16);
    *(uint4*)(out + (size_t)n * D_IN + l * 8) = o;
}

// ---- FUSED 2-layer MLP: out = (relu(A@W1+b1))@W2 + b2 + feat ----
// r8 post-mortem: depth-1 W prefetch ~= 0 gain (76->74.5us); bank conflicts
// identical across two different LDS layouts (2086656 in r6 AND r8) and only
// ~3.4us total -> NOT the bottleneck. Still latency-bound on the W fragment
// stream (MfmaUtil 10.7%, per-half compute ~100-150cy << ~400cy L2 latency).
// THIS ROUND:
//  (a) DEPTH-3 W PIPELINE: fw[3][4] sets, round-robin in a fully-unrolled
//      loop (i%3 folds to constants -> registers, no scratch). Set loaded at
//      iter i is consumed at i+3 -> ~2 full iterations (~300-400cy) of cover,
//      matching the L2 round trip. VGPR +48 (r8 was 64; acc lives in AGPRs)
//      -> ~110 <= 128 keeps 4 waves/SIMD at 1024 thr.
//  (b) PER-WAVE K-STAGGER: wave w sweeps halves starting at 2*(w&7) (phase1)
//      / 4*(w&7) (phase2), wrapping mod 16/32. Accumulation order-independent;
//      desynchronizes the 16 waves' load bursts (no L1/queue convoy).
//  Sync structure, staging, h-write, epilogue, chain: identical to r8.
// LDS: sA 48xPA + sH 48xPH = 148,992B -> 1 block/CU.
// D-layout (proven r6/r8): D = mfma(W_frag, act_frag) -> out-col = lane
// lq*4+r (packed stores), act-row = lane lr.
__global__ __launch_bounds__(1024) void fused_mlp_k(const u16* __restrict__ A,
                                                    const u16* __restrict__ W1T,
                                                    const float* __restrict__ b1,
                                                    const u16* __restrict__ W2T,
                                                    const float* __restrict__ b2,
                                                    const float* __restrict__ feat,
                                                    float* __restrict__ out,
                                                    int M) {
    __shared__ __bf16 sA[48 * PA];
    __shared__ __bf16 sH[48 * PH];

    int row0 = blockIdx.x * 48;
    if (row0 > M - 48) row0 = M - 48;
    const int t = threadIdx.x;
    const int w = t >> 6, l = t & 63;
    const int lr = l & 15, lq = l >> 4;

    // ---- stage A slab: 16 waves x 3 rows; one gload_lds per row ----
#pragma unroll
    for (int q = 0; q < 3; q++) {
        const int row = w * 3 + q;
        const u16* src = A + (size_t)(row0 + row) * 512 + l * 8;
        __builtin_amdgcn_global_load_lds((const AS1 void*)src,
                                         (AS3 void*)(&sA[row * PA]), 16, 0, 0);
    }
    __syncthreads();

    // ---- phase 1: h = relu(A @ W1 + b1); 16 halves of k=32 ----
    const int n1 = w * 64;
    const int off1 = 2 * (w & 7);
    {
        const u16* wb[4];
#pragma unroll
        for (int j = 0; j < 4; j++)
            wb[j] = W1T + (size_t)(n1 + j * 16 + lr) * 512 + lq * 8;

        bf16x8 fw[3][4];
#pragma unroll
        for (int p = 0; p < 3; p++) {
            const int hh = (p + off1) & 15;
#pragma unroll
            for (int j = 0; j < 4; j++)
                fw[p][j] = *(const bf16x8*)(wb[j] + hh * 32);
        }

        f32x4 acc[3][4] = {};
#pragma unroll
        for (int i = 0; i < 16; i++) {
            const int sx = i % 3;                 // constant after unroll
            const int hh = (i + off1) & 15;
            bf16x8 fa[3];
#pragma unroll
            for (int r = 0; r < 3; r++)
                fa[r] = *(const bf16x8*)(&sA[(r * 16 + lr) * PA + hh * 32 + lq * 8]);
            __builtin_amdgcn_s_setprio(1);
#pragma unroll
            for (int r = 0; r < 3; r++)
#pragma unroll
                for (int j = 0; j < 4; j++)
                    acc[r][j] = __builtin_amdgcn_mfma_f32_16x16x32_bf16(
                        fw[sx][j], fa[r], acc[r][j], 0, 0, 0);
            __builtin_amdgcn_s_setprio(0);
            if (i + 3 < 16) {
                const int hn = (i + 3 + off1) & 15;
#pragma unroll
                for (int j = 0; j < 4; j++)
                    fw[sx][j] = *(const bf16x8*)(wb[j] + hn * 32);
            }
        }
        // h-write: lane holds 4 consecutive h-cols at row i*16+lr -> one
        // 8B packed store into the padded row
#pragma unroll
        for (int r = 0; r < 3; r++) {
            const int hrow = r * 16 + lr;
#pragma unroll
            for (int j = 0; j < 4; j++) {
                const int colb = n1 + j * 16 + lq * 4;
                float4 bv = *(const float4*)(b1 + colb);
                float v0 = fmaxf(acc[r][j][0] + bv.x, 0.0f);
                float v1 = fmaxf(acc[r][j][1] + bv.y, 0.0f);
                float v2 = fmaxf(acc[r][j][2] + bv.z, 0.0f);
                float v3 = fmaxf(acc[r][j][3] + bv.w, 0.0f);
                uint2 pv;
                pv.x = (u32)f2bf(v0) | ((u32)f2bf(v1) << 16);
                pv.y = (u32)f2bf(v2) | ((u32)f2bf(v3) << 16);
                *(uint2*)((u16*)sH + hrow * PH + colb) = pv;
            }
        }
    }
    __syncthreads();

    // ---- phase 2: out = h @ W2 + b2 + feat; 32 halves of k=32 ----
    const int n2 = w * 32;
    const int off2 = 4 * (w & 7);
    {
        const u16* vb[2];
#pragma unroll
        for (int j = 0; j < 2; j++)
            vb[j] = W2T + (size_t)(n2 + j * 16 + lr) * 1024 + lq * 8;

        bf16x8 gw[3][2];
#pragma unroll
        for (int p = 0; p < 3; p++) {
            const int hh = (p + off2) & 31;
#pragma unroll
            for (int j = 0; j < 2; j++)
                gw[p][j] = *(const bf16x8*)(vb[j] + hh * 32);
        }

        f32x4 acc[3][2] = {};
#pragma unroll
        for (int i = 0; i < 32; i++) {
            const int sx = i % 3;
            const int hh = (i + off2) & 31;
            bf16x8 fh[3];
#pragma unroll
            for (int r = 0; r < 3; r++)
                fh[r] = *(const bf16x8*)(&sH[(r * 16 + lr) * PH + hh * 32 + lq * 8]);
            __builtin_amdgcn_s_setprio(1);
#pragma unroll
            for (int r = 0; r < 3; r++)
#pragma unroll
                for (int j = 0; j < 2; j++)
                    acc[r][j] = __builtin_amdgcn_mfma_f32_16x16x32_bf16(
                        gw[sx][j], fh[r], acc[r][j], 0, 0, 0);
            __builtin_amdgcn_s_setprio(0);
            if (i + 3 < 32) {
                const int hn = (i + 3 + off2) & 31;
#pragma unroll
                for (int j = 0; j < 2; j++)
                    gw[sx][j] = *(const bf16x8*)(vb[j] + hn * 32);
            }
        }
        // epilogue: float4 stores; wave covers cols n2..n2+31 per row
#pragma unroll
        for (int r = 0; r < 3; r++) {
            const int row = row0 + r * 16 + lr;
#pragma unroll
            for (int j = 0; j < 2; j++) {
                const int colb = n2 + j * 16 + lq * 4;
                float4 bv = *(const float4*)(b2 + colb);
                float4 fv = *(const float4*)(feat + (size_t)row * 512 + colb);
                float4 o;
                o.x = acc[r][j][0] + bv.x + fv.x;
                o.y = acc[r][j][1] + bv.y + fv.y;
                o.z = acc[r][j][2] + bv.z + fv.z;
                o.w = acc[r][j][3] + bv.w + fv.w;
                *(float4*)(out + (size_t)row * 512 + colb) = o;
            }
        }
    }
}

extern "C" void kernel_launch(void* const* d_in, const int* in_sizes, int n_in,
                              void* d_out, int out_size, void* d_ws, size_t ws_size,
                              hipStream_t stream) {
    const float* feat = (const float*)d_in[0];
    const float* W1   = (const float*)d_in[1];
    const float* b1   = (const float*)d_in[2];
    const float* W2   = (const float*)d_in[3];
    const float* b2   = (const float*)d_in[4];
    const float* eps  = (const float*)d_in[5];
    const int*   src  = (const int*)d_in[6];
    const int*   dst  = (const int*)d_in[7];
    float* out = (float*)d_out;

    char* ws = (char*)d_ws;
    u16* rst_b16 = (u16*)(ws);                        // 10,240,000 B
    u16* featb   = (u16*)(ws + 30720000);             // 10,240,000 B
    u16* w1t     = (u16*)(ws + 40960000);             //  1,048,576 B
    u16* w2t     = (u16*)(ws + 42008576);             //  1,048,576 B
    int* counts  = (int*)(ws + 43057152);             //     40,000 B
    int* offs    = (int*)(ws + 43097152);             //     40,004 B
    int* cursor  = (int*)(ws + 43137160);             //     40,000 B
    int* ssrc    = (int*)(ws + 43177160);             //    640,000 B

    const int NE = N_NODES * D_IN;  // 5,120,000

    hipMemsetAsync(counts, 0, N_NODES * sizeof(int), stream);
    hist_k<<<(N_EDGES + 255) / 256, 256, 0, stream>>>(dst, counts);
    scan_k<<<1, 1024, 0, stream>>>(counts, offs, cursor);
    reorder_k<<<(N_EDGES + 255) / 256, 256, 0, stream>>>(src, dst, cursor, ssrc);

    cvt_bf16_k<<<NE / 8 / 256, 256, 0, stream>>>(feat, featb, NE);
    transw_k<<<1024, dim3(32, 8), 0, stream>>>(W1, w1t, W2, w2t);

    gather_k<<<(N_NODES + 1) / 2, 128, 0, stream>>>(feat, featb, eps, offs, ssrc, rst_b16);

    const int NB = (N_NODES + 47) / 48;  // 209 slabs (last overlaps)
    fused_mlp_k<<<NB, 1024, 0, stream>>>(rst_b16, w1t, b1, w2t, b2, feat,
                                         out, N_NODES);
}

// Round 10
// 193.915 us; speedup vs baseline: 1.1639x; 1.1639x over previous
//
#include <hip/hip_runtime.h>

typedef unsigned short u16;
typedef unsigned int u32;
typedef __bf16 bf16x8 __attribute__((ext_vector_type(8)));
typedef float f32x4 __attribute__((ext_vector_type(4)));

#define N_NODES 10000
#define N_EDGES 160000
#define D_IN 512
#define D_HID 1024

#define AS1 __attribute__((address_space(1)))
#define AS3 __attribute__((address_space(3)))

__device__ __forceinline__ u16 f2bf(float f) {
    union { float f; u32 u; } v; v.f = f;
    return (u16)((v.u + 0x7fffu + ((v.u >> 16) & 1u)) >> 16);
}
__device__ __forceinline__ float b2f(u32 h) {
    union { u32 u; float f; } v; v.u = h << 16; return v.f;
}

// ---- CSR build: histogram of dst ----
__global__ void hist_k(const int* __restrict__ dst, int* __restrict__ counts) {
    int e = blockIdx.x * 256 + threadIdx.x;
    if (e < N_EDGES) atomicAdd(&counts[dst[e]], 1);
}

// ---- single-block scan via wave shuffles: offs[10001], cursor[10000] ----
__global__ __launch_bounds__(1024) void scan_k(const int* __restrict__ counts,
                                               int* __restrict__ offs,
                                               int* __restrict__ cursor) {
    __shared__ int wpre[16];
    int t = threadIdx.x, l = t & 63, w = t >> 6;
    int base = t * 10;
    int c[10];
    int lsum = 0;
#pragma unroll
    for (int i = 0; i < 10; i++) {
        int idx = base + i;
        c[i] = (idx < N_NODES) ? counts[idx] : 0;
        lsum += c[i];
    }
    int sc = lsum;
#pragma unroll
    for (int d = 1; d < 64; d <<= 1) {
        int v = __shfl_up(sc, d);
        if (l >= d) sc += v;
    }
    __shared__ int wsum[16];
    if (l == 63) wsum[w] = sc;
    __syncthreads();
    if (w == 0 && l < 16) {
        int v = wsum[l];
        int p = v;
#pragma unroll
        for (int d = 1; d < 16; d <<= 1) {
            int u = __shfl_up(p, d);
            if (l >= d) p += u;
        }
        wpre[l] = p - v;
    }
    __syncthreads();
    int run = wpre[w] + sc - lsum;
#pragma unroll
    for (int i = 0; i < 10; i++) {
        int idx = base + i;
        if (idx < N_NODES) { offs[idx] = run; cursor[idx] = run; run += c[i]; }
    }
    if (t == 1023) offs[N_NODES] = wpre[15] + sc;
}

// ---- reorder edges into dst-sorted order ----
__global__ void reorder_k(const int* __restrict__ src, const int* __restrict__ dst,
                          int* __restrict__ cursor, int* __restrict__ ssrc) {
    int e = blockIdx.x * 256 + threadIdx.x;
    if (e >= N_EDGES) return;
    int d = dst[e];
    int pos = atomicAdd(&cursor[d], 1);
    ssrc[pos] = src[e];
}

// ---- fp32 -> bf16 convert (feat copy), 8 elems/thread ----
__global__ void cvt_bf16_k(const float* __restrict__ in, u16* __restrict__ out, int n) {
    int i = (blockIdx.x * 256 + threadIdx.x) * 8;
    if (i >= n) return;
    float4 a = *(const float4*)(in + i);
    float4 b = *(const float4*)(in + i + 4);
    uint4 o;
    o.x = (u32)f2bf(a.x) | ((u32)f2bf(a.y) << 16);
    o.y = (u32)f2bf(a.z) | ((u32)f2bf(a.w) << 16);
    o.z = (u32)f2bf(b.x) | ((u32)f2bf(b.y) << 16);
    o.w = (u32)f2bf(b.z) | ((u32)f2bf(b.w) << 16);
    *(uint4*)(out + i) = o;
}

// ---- fused W1/W2 transpose+convert: WT[n][k] = bf16(W[k][n]) ----
__global__ void transw_k(const float* __restrict__ W1, u16* __restrict__ w1t,
                         const float* __restrict__ W2, u16* __restrict__ w2t) {
    __shared__ float tile[32][33];
    int b = blockIdx.x;
    const float* W; u16* WT; int K, N, nt;
    if (b < 512) { W = W1; WT = w1t; K = D_IN;  N = D_HID; nt = 32; }
    else         { b -= 512; W = W2; WT = w2t; K = D_HID; N = D_IN;  nt = 16; }
    int n0 = (b % nt) * 32, k0 = (b / nt) * 32;
    int tx = threadIdx.x, ty = threadIdx.y;
#pragma unroll
    for (int i = 0; i < 32; i += 8)
        tile[ty + i][tx] = W[(size_t)(k0 + ty + i) * N + n0 + tx];
    __syncthreads();
#pragma unroll
    for (int i = 0; i < 32; i += 8)
        WT[(size_t)(n0 + ty + i) * K + k0 + tx] = f2bf(tile[tx][ty + i]);
}

// ---- gather-sum from bf16 feat + (1+eps)*fp32 self, write bf16 ----
// one wave (64 lanes) per node, 8 bf16 per lane; 8 edges in flight per iter
__global__ __launch_bounds__(128) void gather_k(const float* __restrict__ feat,
                                                const u16* __restrict__ featb,
                                                const float* __restrict__ eps,
                                                const int* __restrict__ offs,
                                                const int* __restrict__ ssrc,
                                                u16* __restrict__ out) {
    int n = (blockIdx.x * 128 + threadIdx.x) >> 6;
    int l = threadIdx.x & 63;
    if (n >= N_NODES) return;
    int beg = offs[n], end = offs[n + 1];
    float s = 1.0f + eps[0];
    float4 s0 = *(const float4*)(feat + (size_t)n * D_IN + l * 8);
    float4 s1 = *(const float4*)(feat + (size_t)n * D_IN + l * 8 + 4);
    float acc[8] = { s * s0.x, s * s0.y, s * s0.z, s * s0.w,
                     s * s1.x, s * s1.y, s * s1.z, s * s1.w };
#define ACC4(v) \
        acc[0] += b2f(v.x & 0xffffu); acc[1] += b2f(v.x >> 16); \
        acc[2] += b2f(v.y & 0xffffu); acc[3] += b2f(v.y >> 16); \
        acc[4] += b2f(v.z & 0xffffu); acc[5] += b2f(v.z >> 16); \
        acc[6] += b2f(v.w & 0xffffu); acc[7] += b2f(v.w >> 16);
    int e = beg;
    for (; e + 8 <= end; e += 8) {
        uint4 v[8];
#pragma unroll
        for (int q = 0; q < 8; q++) {
            int iq = ssrc[e + q];
            v[q] = *(const uint4*)(featb + (size_t)iq * D_IN + l * 8);
        }
#pragma unroll
        for (int q = 0; q < 8; q++) { ACC4(v[q]) }
    }
    for (; e + 4 <= end; e += 4) {
        int i0 = ssrc[e], i1 = ssrc[e + 1], i2 = ssrc[e + 2], i3 = ssrc[e + 3];
        uint4 v0 = *(const uint4*)(featb + (size_t)i0 * D_IN + l * 8);
        uint4 v1 = *(const uint4*)(featb + (size_t)i1 * D_IN + l * 8);
        uint4 v2 = *(const uint4*)(featb + (size_t)i2 * D_IN + l * 8);
        uint4 v3 = *(const uint4*)(featb + (size_t)i3 * D_IN + l * 8);
        ACC4(v0) ACC4(v1) ACC4(v2) ACC4(v3)
    }
    for (; e < end; e++) {
        int i0 = ssrc[e];
        uint4 v0 = *(const uint4*)(featb + (size_t)i0 * D_IN + l * 8);
        ACC4(v0)
    }
#undef ACC4
    uint4 o;
    o.x = (u32)f2bf(acc[0]) | ((u32)f2bf(acc[1]) << 16);
    o.y = (u32)f2bf(acc[2]) | ((u32)f2bf(acc[3]) << 16);
    o.z = (u32)f2bf(acc[4]) | ((u32)f2bf(acc[5]) << 16);
    o.w = (u32)f2bf(acc[6]) | ((u32)f2bf(acc[7]) << 16);
    *(uint4*)(out + (size_t)n * D_IN + l * 8) = o;
}

// ---- GEMM: C[M,N] = A[M,K] @ B[K,N]; A bf16 row-major, BT bf16 [N,K] ----
// 64x64 tile, ONE WAVE PER BLOCK (64 thr), BK=32, 16x16x32 bf16 MFMA.
// r4 (198.9us best) had this structure with BK=64 -> 32KB LDS -> only
// 5 single-wave blocks/CU (1.25 waves/SIMD): the "free-running waves"
// thesis was LDS-throttled, so the per-iter vmcnt(0) L2 wait (~300-600cy)
// had almost nothing to hide behind. BK=32 halves LDS to 16KB -> 10
// blocks/CU (2.5 waves/SIMD), doubling latency cover. Per tile: 8
// gload_lds + 16 MFMA; K templated -> full unroll, static buffer indices.
// Swizzle for 64B rows (re-derived; bank-group occupancy uniform, 8
// lanes/group = minimum, same math as r0's measured-0-conflict layout):
// LDS slot s of row r holds global chunk s^(r&3); staged via pre-swizzled
// global source (lane l: row l>>2, chunk (l&3)^((l>>2)&3)); frag read at
// slot lq^(lr&3). XCD-chunked bijective remap kept (FETCH 51->25MB).
// M-edge: last row-tile overlaps (row0=min(..,M-64)); dup rows benign.
// EPI=0: C = bf16(relu(acc + bias));  EPI=1: C = acc + bias + feat (fp32)
template <int EPI, int K>
__global__ __launch_bounds__(64) void gemm_k(const u16* __restrict__ A,
                                             const u16* __restrict__ BT,
                                             const float* __restrict__ bias,
                                             const float* __restrict__ feat,
                                             void* __restrict__ Cout,
                                             int M, int N) {
    __shared__ __bf16 sA[2][64 * 32];
    __shared__ __bf16 sB[2][64 * 32];

    // ---- XCD-chunked bijective remap (m204) ----
    const int NX = gridDim.x;
    const int nwg = NX * gridDim.y;
    const int flat = blockIdx.y * NX + blockIdx.x;
    const int qq = nwg >> 3, rr8 = nwg & 7;
    const int xcd = flat & 7, idx = flat >> 3;
    const int L = (xcd < rr8 ? xcd * (qq + 1) : rr8 * (qq + 1) + (xcd - rr8) * qq) + idx;
    int row0 = (L / NX) * 64;
    if (row0 > M - 64) row0 = M - 64;   // overlap last tile; dup rows benign
    const int col0 = (L % NX) * 64;

    const int l = threadIdx.x;
    const int lr = l & 15;
    const int lq = l >> 4;

    // staging: seg q covers rows q*16..+15; lane l -> row q*16+(l>>2),
    // global chunk g=(l&3)^((l>>2)&3) (pre-swizzled source; LDS dest linear:
    // (l>>2)*64B + (l&3)*16B == l*16B)
    const int g8 = (((l & 3) ^ ((l >> 2) & 3)) * 8);
    const u16* bA = A  + (size_t)(row0 + (l >> 2)) * K + g8;
    const u16* bB = BT + (size_t)(col0 + (l >> 2)) * K + g8;
    // fragment-read slot: lane (lr,lq) reads chunk lq of row ..+lr at slot
    // lq ^ (r&3) = lq ^ (lr&3)
    const int fo = ((lq ^ (lr & 3)) * 8);

    f32x4 acc[4][4] = {};
    const int NT = K >> 5;   // k-tiles of 32

#define STAGE(buf, kt)                                                         \
    {                                                                          \
        const int ko_ = (kt) << 5;                                             \
        _Pragma("unroll")                                                      \
        for (int q_ = 0; q_ < 4; q_++) {                                       \
            __builtin_amdgcn_global_load_lds(                                  \
                (const AS1 void*)(bA + (size_t)q_ * 16 * K + ko_),             \
                (AS3 void*)(&sA[buf][q_ * 512]), 16, 0, 0);                    \
            __builtin_amdgcn_global_load_lds(                                  \
                (const AS1 void*)(bB + (size_t)q_ * 16 * K + ko_),             \
                (AS3 void*)(&sB[buf][q_ * 512]), 16, 0, 0);                    \
        }                                                                      \
    }

    STAGE(0, 0);

#pragma unroll
    for (int it = 0; it < NT; ++it) {
        const int cur = it & 1;
        // tile it's 8 loads are the only outstanding VMEM ops here
        asm volatile("s_waitcnt vmcnt(0)" ::: "memory");
        __builtin_amdgcn_sched_barrier(0);
        bf16x8 fa[4], fb[4];
#pragma unroll
        for (int i = 0; i < 4; i++)
            fa[i] = *(const bf16x8*)(&sA[cur][0] + (i * 16 + lr) * 32 + fo);
#pragma unroll
        for (int j = 0; j < 4; j++)
            fb[j] = *(const bf16x8*)(&sB[cur][0] + (j * 16 + lr) * 32 + fo);
        __builtin_amdgcn_sched_barrier(0);
        // prefetch next tile into the other buffer (issued after this tile's
        // ds_reads so conservative waits cannot couple it to this compute)
        if (it + 1 < NT) STAGE(cur ^ 1, it + 1);
        __builtin_amdgcn_sched_barrier(0);
#pragma unroll
        for (int i = 0; i < 4; i++)
#pragma unroll
            for (int j = 0; j < 4; j++)
                acc[i][j] = __builtin_amdgcn_mfma_f32_16x16x32_bf16(
                    fa[i], fb[j], acc[i][j], 0, 0, 0);
    }
#undef STAGE

#pragma unroll
    for (int i = 0; i < 4; i++) {
        int rowb = row0 + i * 16 + lq * 4;
#pragma unroll
        for (int j = 0; j < 4; j++) {
            int col = col0 + j * 16 + lr;
            float bv = bias[col];
#pragma unroll
            for (int r = 0; r < 4; r++) {
                int rr = rowb + r;
                float v = acc[i][j][r] + bv;
                if (EPI == 0) {
                    v = fmaxf(v, 0.0f);
                    ((u16*)Cout)[(size_t)rr * N + col] = f2bf(v);
                } else {
                    v += feat[(size_t)rr * N + col];
                    ((float*)Cout)[(size_t)rr * N + col] = v;
                }
            }
        }
    }
}

extern "C" void kernel_launch(void* const* d_in, const int* in_sizes, int n_in,
                              void* d_out, int out_size, void* d_ws, size_t ws_size,
                              hipStream_t stream) {
    const float* feat = (const float*)d_in[0];
    const float* W1   = (const float*)d_in[1];
    const float* b1   = (const float*)d_in[2];
    const float* W2   = (const float*)d_in[3];
    const float* b2   = (const float*)d_in[4];
    const float* eps  = (const float*)d_in[5];
    const int*   src  = (const int*)d_in[6];
    const int*   dst  = (const int*)d_in[7];
    float* out = (float*)d_out;

    char* ws = (char*)d_ws;
    u16* rst_b16 = (u16*)(ws);                        // 10,240,000 B
    u16* h_b16   = (u16*)(ws + 10240000);             // 20,480,000 B
    u16* featb   = (u16*)(ws + 30720000);             // 10,240,000 B
    u16* w1t     = (u16*)(ws + 40960000);             //  1,048,576 B
    u16* w2t     = (u16*)(ws + 42008576);             //  1,048,576 B
    int* counts  = (int*)(ws + 43057152);             //     40,000 B
    int* offs    = (int*)(ws + 43097152);             //     40,004 B
    int* cursor  = (int*)(ws + 43137160);             //     40,000 B
    int* ssrc    = (int*)(ws + 43177160);             //    640,000 B

    const int NE = N_NODES * D_IN;  // 5,120,000

    hipMemsetAsync(counts, 0, N_NODES * sizeof(int), stream);
    hist_k<<<(N_EDGES + 255) / 256, 256, 0, stream>>>(dst, counts);
    scan_k<<<1, 1024, 0, stream>>>(counts, offs, cursor);
    reorder_k<<<(N_EDGES + 255) / 256, 256, 0, stream>>>(src, dst, cursor, ssrc);

    cvt_bf16_k<<<NE / 8 / 256, 256, 0, stream>>>(feat, featb, NE);
    transw_k<<<1024, dim3(32, 8), 0, stream>>>(W1, w1t, W2, w2t);

    gather_k<<<(N_NODES + 1) / 2, 128, 0, stream>>>(feat, featb, eps, offs, ssrc, rst_b16);

    const int MT = (N_NODES + 63) / 64;  // 157 row-tiles (last one overlaps)
    gemm_k<0, D_IN><<<dim3(D_HID / 64, MT), 64, 0, stream>>>(
        rst_b16, w1t, b1, nullptr, (void*)h_b16, N_NODES, D_HID);
    gemm_k<1, D_HID><<<dim3(D_IN / 64, MT), 64, 0, stream>>>(
        h_b16, w2t, b2, feat, (void*)out, N_NODES, D_IN);
}

// Round 11
// 191.943 us; speedup vs baseline: 1.1759x; 1.0103x over previous
//
#include <hip/hip_runtime.h>

typedef unsigned short u16;
typedef unsigned int u32;
typedef __bf16 bf16x8 __attribute__((ext_vector_type(8)));
typedef float f32x4 __attribute__((ext_vector_type(4)));

#define N_NODES 10000
#define N_EDGES 160000
#define D_IN 512
#define D_HID 1024

#define AS1 __attribute__((address_space(1)))
#define AS3 __attribute__((address_space(3)))

__device__ __forceinline__ u16 f2bf(float f) {
    union { float f; u32 u; } v; v.f = f;
    return (u16)((v.u + 0x7fffu + ((v.u >> 16) & 1u)) >> 16);
}
__device__ __forceinline__ float b2f(u32 h) {
    union { u32 u; float f; } v; v.u = h << 16; return v.f;
}

// ---- CSR build: histogram of dst ----
__global__ void hist_k(const int* __restrict__ dst, int* __restrict__ counts) {
    int e = blockIdx.x * 256 + threadIdx.x;
    if (e < N_EDGES) atomicAdd(&counts[dst[e]], 1);
}

// ---- single-block scan via wave shuffles: offs[10001], cursor[10000] ----
__global__ __launch_bounds__(1024) void scan_k(const int* __restrict__ counts,
                                               int* __restrict__ offs,
                                               int* __restrict__ cursor) {
    __shared__ int wpre[16];
    int t = threadIdx.x, l = t & 63, w = t >> 6;
    int base = t * 10;
    int c[10];
    int lsum = 0;
#pragma unroll
    for (int i = 0; i < 10; i++) {
        int idx = base + i;
        c[i] = (idx < N_NODES) ? counts[idx] : 0;
        lsum += c[i];
    }
    int sc = lsum;
#pragma unroll
    for (int d = 1; d < 64; d <<= 1) {
        int v = __shfl_up(sc, d);
        if (l >= d) sc += v;
    }
    __shared__ int wsum[16];
    if (l == 63) wsum[w] = sc;
    __syncthreads();
    if (w == 0 && l < 16) {
        int v = wsum[l];
        int p = v;
#pragma unroll
        for (int d = 1; d < 16; d <<= 1) {
            int u = __shfl_up(p, d);
            if (l >= d) p += u;
        }
        wpre[l] = p - v;
    }
    __syncthreads();
    int run = wpre[w] + sc - lsum;
#pragma unroll
    for (int i = 0; i < 10; i++) {
        int idx = base + i;
        if (idx < N_NODES) { offs[idx] = run; cursor[idx] = run; run += c[i]; }
    }
    if (t == 1023) offs[N_NODES] = wpre[15] + sc;
}

// ---- reorder edges into dst-sorted order ----
__global__ void reorder_k(const int* __restrict__ src, const int* __restrict__ dst,
                          int* __restrict__ cursor, int* __restrict__ ssrc) {
    int e = blockIdx.x * 256 + threadIdx.x;
    if (e >= N_EDGES) return;
    int d = dst[e];
    int pos = atomicAdd(&cursor[d], 1);
    ssrc[pos] = src[e];
}

// ---- fp32 -> bf16 convert (feat copy), 8 elems/thread ----
__global__ void cvt_bf16_k(const float* __restrict__ in, u16* __restrict__ out, int n) {
    int i = (blockIdx.x * 256 + threadIdx.x) * 8;
    if (i >= n) return;
    float4 a = *(const float4*)(in + i);
    float4 b = *(const float4*)(in + i + 4);
    uint4 o;
    o.x = (u32)f2bf(a.x) | ((u32)f2bf(a.y) << 16);
    o.y = (u32)f2bf(a.z) | ((u32)f2bf(a.w) << 16);
    o.z = (u32)f2bf(b.x) | ((u32)f2bf(b.y) << 16);
    o.w = (u32)f2bf(b.z) | ((u32)f2bf(b.w) << 16);
    *(uint4*)(out + i) = o;
}

// ---- fused W1/W2 transpose+convert: WT[n][k] = bf16(W[k][n]) ----
__global__ void transw_k(const float* __restrict__ W1, u16* __restrict__ w1t,
                         const float* __restrict__ W2, u16* __restrict__ w2t) {
    __shared__ float tile[32][33];
    int b = blockIdx.x;
    const float* W; u16* WT; int K, N, nt;
    if (b < 512) { W = W1; WT = w1t; K = D_IN;  N = D_HID; nt = 32; }
    else         { b -= 512; W = W2; WT = w2t; K = D_HID; N = D_IN;  nt = 16; }
    int n0 = (b % nt) * 32, k0 = (b / nt) * 32;
    int tx = threadIdx.x, ty = threadIdx.y;
#pragma unroll
    for (int i = 0; i < 32; i += 8)
        tile[ty + i][tx] = W[(size_t)(k0 + ty + i) * N + n0 + tx];
    __syncthreads();
#pragma unroll
    for (int i = 0; i < 32; i += 8)
        WT[(size_t)(n0 + ty + i) * K + k0 + tx] = f2bf(tile[tx][ty + i]);
}

// ---- gather-sum from bf16 feat + (1+eps)*fp32 self, write bf16 ----
// one wave (64 lanes) per node, 8 bf16 per lane; 8 edges in flight per iter
__global__ __launch_bounds__(128) void gather_k(const float* __restrict__ feat,
                                                const u16* __restrict__ featb,
                                                const float* __restrict__ eps,
                                                const int* __restrict__ offs,
                                                const int* __restrict__ ssrc,
                                                u16* __restrict__ out) {
    int n = (blockIdx.x * 128 + threadIdx.x) >> 6;
    int l = threadIdx.x & 63;
    if (n >= N_NODES) return;
    int beg = offs[n], end = offs[n + 1];
    float s = 1.0f + eps[0];
    float4 s0 = *(const float4*)(feat + (size_t)n * D_IN + l * 8);
    float4 s1 = *(const float4*)(feat + (size_t)n * D_IN + l * 8 + 4);
    float acc[8] = { s * s0.x, s * s0.y, s * s0.z, s * s0.w,
                     s * s1.x, s * s1.y, s * s1.z, s * s1.w };
#define ACC4(v) \
        acc[0] += b2f(v.x & 0xffffu); acc[1] += b2f(v.x >> 16); \
        acc[2] += b2f(v.y & 0xffffu); acc[3] += b2f(v.y >> 16); \
        acc[4] += b2f(v.z & 0xffffu); acc[5] += b2f(v.z >> 16); \
        acc[6] += b2f(v.w & 0xffffu); acc[7] += b2f(v.w >> 16);
    int e = beg;
    for (; e + 8 <= end; e += 8) {
        uint4 v[8];
#pragma unroll
        for (int q = 0; q < 8; q++) {
            int iq = ssrc[e + q];
            v[q] = *(const uint4*)(featb + (size_t)iq * D_IN + l * 8);
        }
#pragma unroll
        for (int q = 0; q < 8; q++) { ACC4(v[q]) }
    }
    for (; e + 4 <= end; e += 4) {
        int i0 = ssrc[e], i1 = ssrc[e + 1], i2 = ssrc[e + 2], i3 = ssrc[e + 3];
        uint4 v0 = *(const uint4*)(featb + (size_t)i0 * D_IN + l * 8);
        uint4 v1 = *(const uint4*)(featb + (size_t)i1 * D_IN + l * 8);
        uint4 v2 = *(const uint4*)(featb + (size_t)i2 * D_IN + l * 8);
        uint4 v3 = *(const uint4*)(featb + (size_t)i3 * D_IN + l * 8);
        ACC4(v0) ACC4(v1) ACC4(v2) ACC4(v3)
    }
    for (; e < end; e++) {
        int i0 = ssrc[e];
        uint4 v0 = *(const uint4*)(featb + (size_t)i0 * D_IN + l * 8);
        ACC4(v0)
    }
#undef ACC4
    uint4 o;
    o.x = (u32)f2bf(acc[0]) | ((u32)f2bf(acc[1]) << 16);
    o.y = (u32)f2bf(acc[2]) | ((u32)f2bf(acc[3]) << 16);
    o.z = (u32)f2bf(acc[4]) | ((u32)f2bf(acc[5]) << 16);
    o.w = (u32)f2bf(acc[6]) | ((u32)f2bf(acc[7]) << 16);
    *(uint4*)(out + (size_t)n * D_IN + l * 8) = o;
}

// ---- GEMM: C[M,N] = A[M,K] @ B[K,N]; A bf16 row-major, BT bf16 [N,K] ----
// 64x64 tile, ONE WAVE PER BLOCK (64 thr), BK=32, 16x16x32 bf16 MFMA.
// r10 post-mortem: TLP doubling (BK64->32) bought only ~5us => residual is
// each wave's OWN per-iter latency chain: vmcnt(0) drains loads issued only
// ~100cy earlier (the MFMA window). THIS ROUND: depth-2 pipeline with EXACT
// counted waits -- safe here because each block is one wave issuing no other
// VMEM in the loop, so the vmcnt arithmetic is provably exact (unlike the
// multi-wave r1/r3 attempts): 3 LDS buffers (24KB -> 6 blocks/CU), prologue
// stages tiles 0,1; iter it waits vmcnt(8) (tile it's 8 loads done; tile
// it+1's 8 remain in flight), ds_reads buf[it%3], stages tile it+2 into
// buf[(it+2)%3] (distinct from both live buffers; its previous reader
// retired >=1 iter ago in program order), MFMAs. Each tile gets ~2 full
// iterations of flight (~500-800cy) vs ~100cy before. Last iter: vmcnt(0)
// (static -- loop fully unrolled). Swizzle/staging/XCD remap: r10 verbatim.
// EPI=0: C = bf16(relu(acc + bias));  EPI=1: C = acc + bias + feat (fp32)
template <int EPI, int K>
__global__ __launch_bounds__(64) void gemm_k(const u16* __restrict__ A,
                                             const u16* __restrict__ BT,
                                             const float* __restrict__ bias,
                                             const float* __restrict__ feat,
                                             void* __restrict__ Cout,
                                             int M, int N) {
    __shared__ __bf16 sA[3][64 * 32];
    __shared__ __bf16 sB[3][64 * 32];

    // ---- XCD-chunked bijective remap (m204) ----
    const int NX = gridDim.x;
    const int nwg = NX * gridDim.y;
    const int flat = blockIdx.y * NX + blockIdx.x;
    const int qq = nwg >> 3, rr8 = nwg & 7;
    const int xcd = flat & 7, idx = flat >> 3;
    const int L = (xcd < rr8 ? xcd * (qq + 1) : rr8 * (qq + 1) + (xcd - rr8) * qq) + idx;
    int row0 = (L / NX) * 64;
    if (row0 > M - 64) row0 = M - 64;   // overlap last tile; dup rows benign
    const int col0 = (L % NX) * 64;

    const int l = threadIdx.x;
    const int lr = l & 15;
    const int lq = l >> 4;

    // staging: seg q covers rows q*16..+15; lane l -> row q*16+(l>>2),
    // global chunk g=(l&3)^((l>>2)&3) (pre-swizzled source; LDS dest linear)
    const int g8 = (((l & 3) ^ ((l >> 2) & 3)) * 8);
    const u16* bA = A  + (size_t)(row0 + (l >> 2)) * K + g8;
    const u16* bB = BT + (size_t)(col0 + (l >> 2)) * K + g8;
    // fragment-read slot: lane (lr,lq) reads chunk lq of row ..+lr at slot
    // lq ^ (r&3) = lq ^ (lr&3)
    const int fo = ((lq ^ (lr & 3)) * 8);

    f32x4 acc[4][4] = {};
    const int NT = K >> 5;   // k-tiles of 32

#define STAGE(buf, kt)                                                         \
    {                                                                          \
        const int ko_ = (kt) << 5;                                             \
        _Pragma("unroll")                                                      \
        for (int q_ = 0; q_ < 4; q_++) {                                       \
            __builtin_amdgcn_global_load_lds(                                  \
                (const AS1 void*)(bA + (size_t)q_ * 16 * K + ko_),             \
                (AS3 void*)(&sA[buf][q_ * 512]), 16, 0, 0);                    \
            __builtin_amdgcn_global_load_lds(                                  \
                (const AS1 void*)(bB + (size_t)q_ * 16 * K + ko_),             \
                (AS3 void*)(&sB[buf][q_ * 512]), 16, 0, 0);                    \
        }                                                                      \
    }

    // prologue: 2 tiles in flight (16 loads)
    STAGE(0, 0);
    STAGE(1, 1);

#pragma unroll
    for (int it = 0; it < NT; ++it) {
        const int cur = it % 3;            // constant after full unroll
        // exact counted wait: outstanding = tiles it, it+1 (16 loads);
        // vmcnt(8) completes tile it, leaves it+1 in flight. Last iter has
        // only 8 outstanding -> needs vmcnt(0).
        if (it == NT - 1) {
            asm volatile("s_waitcnt vmcnt(0)" ::: "memory");
        } else {
            asm volatile("s_waitcnt vmcnt(8)" ::: "memory");
        }
        __builtin_amdgcn_sched_barrier(0);
        bf16x8 fa[4], fb[4];
#pragma unroll
        for (int i = 0; i < 4; i++)
            fa[i] = *(const bf16x8*)(&sA[cur][0] + (i * 16 + lr) * 32 + fo);
#pragma unroll
        for (int j = 0; j < 4; j++)
            fb[j] = *(const bf16x8*)(&sB[cur][0] + (j * 16 + lr) * 32 + fo);
        __builtin_amdgcn_sched_barrier(0);
        // stage tile it+2 into buf[(it+2)%3]: distinct from buf[it%3] and
        // buf[(it+1)%3]; its previous reader (tile it-1) retired before
        // tile it-1's MFMAs, which precede this point in program order
        if (it + 2 < NT) STAGE((it + 2) % 3, it + 2);
        __builtin_amdgcn_sched_barrier(0);
#pragma unroll
        for (int i = 0; i < 4; i++)
#pragma unroll
            for (int j = 0; j < 4; j++)
                acc[i][j] = __builtin_amdgcn_mfma_f32_16x16x32_bf16(
                    fa[i], fb[j], acc[i][j], 0, 0, 0);
    }
#undef STAGE

#pragma unroll
    for (int i = 0; i < 4; i++) {
        int rowb = row0 + i * 16 + lq * 4;
#pragma unroll
        for (int j = 0; j < 4; j++) {
            int col = col0 + j * 16 + lr;
            float bv = bias[col];
#pragma unroll
            for (int r = 0; r < 4; r++) {
                int rr = rowb + r;
                float v = acc[i][j][r] + bv;
                if (EPI == 0) {
                    v = fmaxf(v, 0.0f);
                    ((u16*)Cout)[(size_t)rr * N + col] = f2bf(v);
                } else {
                    v += feat[(size_t)rr * N + col];
                    ((float*)Cout)[(size_t)rr * N + col] = v;
                }
            }
        }
    }
}

extern "C" void kernel_launch(void* const* d_in, const int* in_sizes, int n_in,
                              void* d_out, int out_size, void* d_ws, size_t ws_size,
                              hipStream_t stream) {
    const float* feat = (const float*)d_in[0];
    const float* W1   = (const float*)d_in[1];
    const float* b1   = (const float*)d_in[2];
    const float* W2   = (const float*)d_in[3];
    const float* b2   = (const float*)d_in[4];
    const float* eps  = (const float*)d_in[5];
    const int*   src  = (const int*)d_in[6];
    const int*   dst  = (const int*)d_in[7];
    float* out = (float*)d_out;

    char* ws = (char*)d_ws;
    u16* rst_b16 = (u16*)(ws);                        // 10,240,000 B
    u16* h_b16   = (u16*)(ws + 10240000);             // 20,480,000 B
    u16* featb   = (u16*)(ws + 30720000);             // 10,240,000 B
    u16* w1t     = (u16*)(ws + 40960000);             //  1,048,576 B
    u16* w2t     = (u16*)(ws + 42008576);             //  1,048,576 B
    int* counts  = (int*)(ws + 43057152);             //     40,000 B
    int* offs    = (int*)(ws + 43097152);             //     40,004 B
    int* cursor  = (int*)(ws + 43137160);             //     40,000 B
    int* ssrc    = (int*)(ws + 43177160);             //    640,000 B

    const int NE = N_NODES * D_IN;  // 5,120,000

    hipMemsetAsync(counts, 0, N_NODES * sizeof(int), stream);
    hist_k<<<(N_EDGES + 255) / 256, 256, 0, stream>>>(dst, counts);
    scan_k<<<1, 1024, 0, stream>>>(counts, offs, cursor);
    reorder_k<<<(N_EDGES + 255) / 256, 256, 0, stream>>>(src, dst, cursor, ssrc);

    cvt_bf16_k<<<NE / 8 / 256, 256, 0, stream>>>(feat, featb, NE);
    transw_k<<<1024, dim3(32, 8), 0, stream>>>(W1, w1t, W2, w2t);

    gather_k<<<(N_NODES + 1) / 2, 128, 0, stream>>>(feat, featb, eps, offs, ssrc, rst_b16);

    const int MT = (N_NODES + 63) / 64;  // 157 row-tiles (last one overlaps)
    gemm_k<0, D_IN><<<dim3(D_HID / 64, MT), 64, 0, stream>>>(
        rst_b16, w1t, b1, nullptr, (void*)h_b16, N_NODES, D_HID);
    gemm_k<1, D_HID><<<dim3(D_IN / 64, MT), 64, 0, stream>>>(
        h_b16, w2t, b2, feat, (void*)out, N_NODES, D_IN);
}